// Round 10
// baseline (109.954 us; speedup 1.0000x reference)
//
#include <hip/hip_runtime.h>

#define NN 17    // nodes
#define D  512   // feature dim
#define H  8     // heads
#define C1 515   // D + 3
#define M  256   // hidden

#define XPAD 20                              // [d][n] row stride (17 + pad)
#define RSN  36                              // reduction row: 32 outputs + pad
#define RSG  (NN * RSN)                      // 612 floats per group (2448 B, 16B-mult)
#define SMEM_FL (32 * RSG)                   // 19584 floats = 78.3 KB (union buffer)

__device__ __forceinline__ void fma4(float4& a, float x, const float4& w) {
    a.x = fmaf(x, w.x, a.x); a.y = fmaf(x, w.y, a.y);
    a.z = fmaf(x, w.z, a.z); a.w = fmaf(x, w.w, a.w);
}

// K1: f[h,n,e] = relu(Xs @ FC[h]); FC read exactly once.
// grid = H*16 (e-tiles of 32), block = 256. tw=t&7 -> float4 e; cg=t>>3 (32
// groups) -> d = cg + 32*i. Per-thread: 17 float4 accumulators.
__global__ __launch_bounds__(256) void k1_f(const float* __restrict__ Xs,
                                            const float* __restrict__ FC,
                                            float* __restrict__ f) {
    const int b = blockIdx.x;
    const int et = b & 15, h = b >> 4;
    const int t = threadIdx.x, tw = t & 7, cg = t >> 3;
    __shared__ __align__(16) float sm[SMEM_FL];   // ph1: xs_t [d][XPAD]; ph2: red
    for (int i = t; i < NN * D; i += 256) {
        const int n = i >> 9, d = i & 511;
        sm[d * XPAD + n] = Xs[i];
    }
    __syncthreads();
    float4 acc[NN];
#pragma unroll
    for (int n = 0; n < NN; ++n) acc[n] = make_float4(0.f, 0.f, 0.f, 0.f);
    const float4* fc4 = (const float4*)(FC + (size_t)h * D * D) + et * 8 + tw;
#pragma unroll 4
    for (int i = 0; i < 16; ++i) {
        const int d = cg + (i << 5);
        const float4 w = fc4[d << 7];            // [d][512/4] row stride 128
        const float* xr = sm + d * XPAD;
#pragma unroll
        for (int n4 = 0; n4 < 4; ++n4) {
            const float4 x = *(const float4*)(xr + (n4 << 2));
            fma4(acc[n4 * 4 + 0], x.x, w);
            fma4(acc[n4 * 4 + 1], x.y, w);
            fma4(acc[n4 * 4 + 2], x.z, w);
            fma4(acc[n4 * 4 + 3], x.w, w);
        }
        fma4(acc[16], xr[16], w);
    }
    __syncthreads();                 // xs reads done; reuse smem for reduction
    float* rr = sm + cg * RSG + tw * 4;
#pragma unroll
    for (int n = 0; n < NN; ++n) *(float4*)(rr + n * RSN) = acc[n];
    __syncthreads();
    for (int i = t; i < NN * 32; i += 256) {
        const int n = i >> 5, e = i & 31;
        float s = 0.f;
#pragma unroll 8
        for (int g = 0; g < 32; ++g) s += sm[g * RSG + n * RSN + e];
        f[((h * NN + n) << 9) + (et << 5) + e] = fmaxf(s, 0.f);
    }
}

// K2: hdn[h,n,m] = tanh([f,ROI] @ W1[h] + b1[h]); W1 read exactly once.
// grid = H*8 (m-tiles of 32), block = 256; c = cg + 32*i, tail c=512+cg (cg<3).
__global__ __launch_bounds__(256) void k2_hdn(const float* __restrict__ f,
                                              const float* __restrict__ ROIs,
                                              const float* __restrict__ W1,
                                              const float* __restrict__ b1,
                                              float* __restrict__ hdn) {
    const int b = blockIdx.x;
    const int mt = b & 7, h = b >> 3;
    const int t = threadIdx.x, tw = t & 7, cg = t >> 3;
    __shared__ __align__(16) float sm[SMEM_FL];
    for (int i = t; i < NN * D; i += 256) {
        const int n = i >> 9, d = i & 511;
        sm[d * XPAD + n] = f[((size_t)(h * NN) << 9) + i];
    }
    if (t < NN * 3) {
        const int n = t / 3, cc = t % 3;
        sm[(D + cc) * XPAD + n] = ROIs[t];
    }
    __syncthreads();
    float4 acc[NN];
#pragma unroll
    for (int n = 0; n < NN; ++n) acc[n] = make_float4(0.f, 0.f, 0.f, 0.f);
    const float4* w4 = (const float4*)(W1 + (size_t)h * C1 * M) + mt * 8 + tw;
#pragma unroll 4
    for (int i = 0; i < 16; ++i) {
        const int c = cg + (i << 5);
        const float4 w = w4[c << 6];             // [c][256/4] row stride 64
        const float* xr = sm + c * XPAD;
#pragma unroll
        for (int n4 = 0; n4 < 4; ++n4) {
            const float4 x = *(const float4*)(xr + (n4 << 2));
            fma4(acc[n4 * 4 + 0], x.x, w);
            fma4(acc[n4 * 4 + 1], x.y, w);
            fma4(acc[n4 * 4 + 2], x.z, w);
            fma4(acc[n4 * 4 + 3], x.w, w);
        }
        fma4(acc[16], xr[16], w);
    }
    if (cg < 3) {                                // tail rows c = 512..514 (ROI)
        const int c = D + cg;
        const float4 w = w4[c << 6];
        const float* xr = sm + c * XPAD;
#pragma unroll
        for (int n4 = 0; n4 < 4; ++n4) {
            const float4 x = *(const float4*)(xr + (n4 << 2));
            fma4(acc[n4 * 4 + 0], x.x, w);
            fma4(acc[n4 * 4 + 1], x.y, w);
            fma4(acc[n4 * 4 + 2], x.z, w);
            fma4(acc[n4 * 4 + 3], x.w, w);
        }
        fma4(acc[16], xr[16], w);
    }
    __syncthreads();
    float* rr = sm + cg * RSG + tw * 4;
#pragma unroll
    for (int n = 0; n < NN; ++n) *(float4*)(rr + n * RSN) = acc[n];
    __syncthreads();
    for (int i = t; i < NN * 32; i += 256) {
        const int n = i >> 5, m = i & 31;
        float s = b1[h * M + (mt << 5) + m];
#pragma unroll 8
        for (int g = 0; g < 32; ++g) s += sm[g * RSG + n * RSN + m];
        hdn[(h * NN + n) * M + (mt << 5) + m] = tanhf(s);
    }
}

// K34 (fused k3+k4): one block per landmark k.
// Phase 1: scores[h,n] = hdn[h,n,:].W2[h,:,k] + b2[h,k] (W2 col staged in LDS)
// Phase 2: softmax over n per h  ->  att weights in LDS
// Phase 3: out[k,d] = relu(sum_h cw[h]*sum_n att[h,n]*f[h,n,d] + cb) + Xs[k,d]
// grid = NN blocks, block = 256 (each thread covers d = t and t+256).
__global__ __launch_bounds__(256) void k34(const float* __restrict__ hdn,
                                           const float* __restrict__ W2,
                                           const float* __restrict__ b2,
                                           const float* __restrict__ f,
                                           const float* __restrict__ conv_w,
                                           const float* __restrict__ conv_b,
                                           const float* __restrict__ Xs,
                                           const float* __restrict__ ROIs,
                                           float* __restrict__ out) {
    const int k = blockIdx.x, t = threadIdx.x;
    __shared__ float swk[H][M + 4];   // W2[h,:,k], row stride 260 (16B-mult)
    __shared__ float sa[H][NN];       // scores -> att weights
    __shared__ float cw[H];
    for (int i = t; i < H * M; i += 256) {
        const int h = i >> 8, m = i & 255;
        swk[h][m] = W2[(size_t)(h * M + m) * NN + k];
    }
    if (t < H) cw[t] = conv_w[t];
    __syncthreads();
    if (t < H * NN) {
        const int h = t / NN, n = t % NN;
        const float4* a4 = (const float4*)(hdn + (h * NN + n) * M);
        const float4* w4 = (const float4*)(&swk[h][0]);
        float acc = b2[h * NN + k];
#pragma unroll 8
        for (int m4 = 0; m4 < M / 4; ++m4) {
            const float4 av = a4[m4];
            const float4 wv = w4[m4];
            acc = fmaf(av.x, wv.x, acc); acc = fmaf(av.y, wv.y, acc);
            acc = fmaf(av.z, wv.z, acc); acc = fmaf(av.w, wv.w, acc);
        }
        sa[h][n] = acc;
    }
    __syncthreads();
    if (t < H) {
        float mx = -1e30f;
#pragma unroll
        for (int n = 0; n < NN; ++n) mx = fmaxf(mx, sa[t][n]);
        float e[NN];
        float s = 0.f;
#pragma unroll
        for (int n = 0; n < NN; ++n) { e[n] = __expf(sa[t][n] - mx); s += e[n]; }
        const float inv = 1.f / s;
#pragma unroll
        for (int n = 0; n < NN; ++n) sa[t][n] = e[n] * inv;
    }
    __syncthreads();
    const float cb = conv_b[0];
    float acc0 = 0.f, acc1 = 0.f;
    for (int h = 0; h < H; ++h) {
        float w0 = 0.f, w1 = 0.f;
#pragma unroll
        for (int n = 0; n < NN; ++n) {
            const float a = sa[h][n];
            const float* fr = f + (size_t)((h * NN + n) << 9);
            w0 = fmaf(a, fr[t], w0);
            w1 = fmaf(a, fr[t + 256], w1);
        }
        acc0 = fmaf(cw[h], w0, acc0);
        acc1 = fmaf(cw[h], w1, acc1);
    }
    out[(k << 9) + t]       = fmaxf(acc0 + cb, 0.f) + Xs[(k << 9) + t];
    out[(k << 9) + t + 256] = fmaxf(acc1 + cb, 0.f) + Xs[(k << 9) + t + 256];
    if (k == 0 && t < NN * 3) out[NN * D + t] = ROIs[t];
}

extern "C" void kernel_launch(void* const* d_in, const int* in_sizes, int n_in,
                              void* d_out, int out_size, void* d_ws, size_t ws_size,
                              hipStream_t stream) {
    const float* Xs     = (const float*)d_in[0];
    const float* ROIs   = (const float*)d_in[1];
    // d_in[2] = adj, unused
    const float* FC     = (const float*)d_in[3];
    const float* W1     = (const float*)d_in[4];
    const float* b1     = (const float*)d_in[5];
    const float* W2     = (const float*)d_in[6];
    const float* b2     = (const float*)d_in[7];
    const float* conv_w = (const float*)d_in[8];
    const float* conv_b = (const float*)d_in[9];
    float* out = (float*)d_out;

    float* f   = (float*)d_ws;                 // H*NN*D  = 69632 floats
    float* hdn = f + H * NN * D;               // H*NN*M  = 34816 floats

    k1_f  <<<H * 16, 256, 0, stream>>>(Xs, FC, f);
    k2_hdn<<<H * 8,  256, 0, stream>>>(f, ROIs, W1, b1, hdn);
    k34   <<<NN,     256, 0, stream>>>(hdn, W2, b2, f, conv_w, conv_b, Xs, ROIs, out);
}